// Round 5
// baseline (252.731 us; speedup 1.0000x reference)
//
#include <hip/hip_runtime.h>

#define NB 4
#define NN 1024
#define CC 64
#define BPB (NN / 4)   // gemm blocks per batch = 256
#define IT 8           // i-rows per bcast block (yc L2-read reuse factor)

typedef float f4_native __attribute__((ext_vector_type(4)));

// Kernel 1: per 4-row block:
//   yc[b,n,o] = sum_c x[b,n,c]*W0[o,c]
//   yr[b,n,o] = sum_c x[b,n,c]*W1[o,c]
//   partials[blk,c] = sum over the block's 4 rows of x[.,c]
__global__ void k_gemm(const float* __restrict__ x, const float* __restrict__ W0,
                       const float* __restrict__ W1,
                       float* __restrict__ yc, float* __restrict__ yr,
                       float* __restrict__ partials) {
    __shared__ float sW0[64][65];   // +1 pad: stride-64 col reads would be 32-way bank conflict
    __shared__ float sW1[64][65];
    __shared__ float sX[4][64];
    const int t = threadIdx.x;
    const int b = blockIdx.x / BPB;
    const int n0 = (blockIdx.x % BPB) * 4;
    for (int idx = t; idx < 64 * 64; idx += 256) {
        sW0[idx >> 6][idx & 63] = W0[idx];
        sW1[idx >> 6][idx & 63] = W1[idx];
    }
    const int o = t & 63, r = t >> 6;
    sX[r][o] = x[((size_t)(b * NN + n0 + r)) * CC + o];
    __syncthreads();
    float a0 = 0.f, a1 = 0.f;
    #pragma unroll
    for (int c = 0; c < 64; ++c) {
        const float xv = sX[r][c];
        a0 += xv * sW0[o][c];
        a1 += xv * sW1[o][c];
    }
    const size_t oidx = ((size_t)(b * NN + n0 + r)) * CC + o;
    yc[oidx] = a0;
    yr[oidx] = a1;
    if (r == 0)   // threads 0..63: column partial sum of this block's 4 rows
        partials[(size_t)blockIdx.x * 64 + o] =
            sX[0][o] + sX[1][o] + sX[2][o] + sX[3][o];
}

// Kernel 2 (tiny): reduce partials per batch -> xsum, then ysb[b,o] = xsum.W2[o,:] + bias[o]
__global__ void k_ysb(const float* __restrict__ partials, const float* __restrict__ W2,
                      const float* __restrict__ bias, float* __restrict__ ysb) {
    const int b = blockIdx.x;
    const int t = threadIdx.x;
    const int c = t & 63, g = t >> 6;   // 4 groups x 64 channels
    __shared__ float sPart[4][64];
    __shared__ float sXsum[64];
    float acc = 0.f;
    const float* pb = partials + (size_t)b * BPB * 64;
    for (int blk = g; blk < BPB; blk += 4)
        acc += pb[blk * 64 + c];
    sPart[g][c] = acc;
    __syncthreads();
    if (t < 64)
        sXsum[t] = sPart[0][t] + sPart[1][t] + sPart[2][t] + sPart[3][t];
    __syncthreads();
    if (t < 64) {
        float v = bias[t];               // bias shape (64,1) -> bias[o]
        const float* w = W2 + t * CC;
        #pragma unroll 8
        for (int cc = 0; cc < CC; ++cc) v += sXsum[cc] * w[cc];
        ysb[b * CC + t] = v;
    }
}

// Kernel 3: out[b,i,j,:] = yc[b,j,:] + yr[b,i,:] + ysb[b,:]
// IT=8 rows per block: each yc element is loaded from L2 ONCE and stored to 8
// output rows -> yc L2-read traffic drops 8x (4.3 GB -> 0.54 GB).
// Block = 512 threads; wave stores stay 1 KB-contiguous.
__global__ void k_bcast(const float4* __restrict__ yc4, const float4* __restrict__ yr4,
                        const float4* __restrict__ ysb4, float4* __restrict__ out4) {
    const int t  = threadIdx.x;
    const int o4 = t & 15;
    const int j0 = t >> 4;              // 0..31
    const int b  = blockIdx.x / (NN / IT);
    const int i0 = (blockIdx.x % (NN / IT)) * IT;
    const float4 ys = ysb4[b * 16 + o4];
    float4 yrr[IT];
    #pragma unroll
    for (int r = 0; r < IT; ++r) {
        float4 v = yr4[(size_t)(b * NN + i0 + r) * 16 + o4];
        yrr[r].x = v.x + ys.x; yrr[r].y = v.y + ys.y;
        yrr[r].z = v.z + ys.z; yrr[r].w = v.w + ys.w;
    }
    const float4* ycb = yc4 + (size_t)b * NN * 16;
    float4* ob = out4 + (size_t)(b * NN + i0) * (NN * 16);
    #pragma unroll 2
    for (int j = j0; j < NN; j += 32) {
        float4 v = ycb[j * 16 + o4];
        #pragma unroll
        for (int r = 0; r < IT; ++r) {
            float4 w;
            w.x = v.x + yrr[r].x; w.y = v.y + yrr[r].y;
            w.z = v.z + yrr[r].z; w.w = v.w + yrr[r].w;
            __builtin_nontemporal_store(*(const f4_native*)&w,
                                        (f4_native*)&ob[(size_t)r * (NN * 16) + j * 16 + o4]);
        }
    }
}

extern "C" void kernel_launch(void* const* d_in, const int* in_sizes, int n_in,
                              void* d_out, int out_size, void* d_ws, size_t ws_size,
                              hipStream_t stream) {
    const float* x    = (const float*)d_in[0];
    // d_in[1] = adj (unused by forward)
    const float* W0   = (const float*)d_in[2];
    const float* W1   = (const float*)d_in[3];
    const float* W2   = (const float*)d_in[4];
    const float* bias = (const float*)d_in[5];
    float* out = (float*)d_out;

    float* ws       = (float*)d_ws;
    float* ysb      = ws;                                   // 256 floats
    float* yc       = ws + 256;                             // 262144 floats
    float* yr       = yc + NB * NN * CC;                    // 262144 floats
    float* partials = yr + NB * NN * CC;                    // 1024*64 = 65536 floats

    k_gemm<<<NB * BPB, 256, 0, stream>>>(x, W0, W1, yc, yr, partials);
    k_ysb<<<NB, 256, 0, stream>>>(partials, W2, bias, ysb);
    k_bcast<<<NB * (NN / IT), 512, 0, stream>>>((const float4*)yc, (const float4*)yr,
                                                (const float4*)ysb, (float4*)out);
}

// Round 6
// 239.832 us; speedup vs baseline: 1.0538x; 1.0538x over previous
//
#include <hip/hip_runtime.h>

#define NB 4
#define NN 1024
#define CC 64
#define BPB (NN / 4)   // gemm blocks per batch = 256
#define IT 4           // i-rows per bcast block (yc L2-read reuse factor)

typedef float f4_native __attribute__((ext_vector_type(4)));

// Kernel 1: per 4-row block:
//   yc[b,n,o] = sum_c x[b,n,c]*W0[o,c]
//   yr[b,n,o] = sum_c x[b,n,c]*W1[o,c]
//   partials[blk,c] = sum over the block's 4 rows of x[.,c]
__global__ void k_gemm(const float* __restrict__ x, const float* __restrict__ W0,
                       const float* __restrict__ W1,
                       float* __restrict__ yc, float* __restrict__ yr,
                       float* __restrict__ partials) {
    __shared__ float sW0[64][65];   // +1 pad: stride-64 col reads would be 32-way bank conflict
    __shared__ float sW1[64][65];
    __shared__ float sX[4][64];
    const int t = threadIdx.x;
    const int b = blockIdx.x / BPB;
    const int n0 = (blockIdx.x % BPB) * 4;
    for (int idx = t; idx < 64 * 64; idx += 256) {
        sW0[idx >> 6][idx & 63] = W0[idx];
        sW1[idx >> 6][idx & 63] = W1[idx];
    }
    const int o = t & 63, r = t >> 6;
    sX[r][o] = x[((size_t)(b * NN + n0 + r)) * CC + o];
    __syncthreads();
    float a0 = 0.f, a1 = 0.f;
    #pragma unroll
    for (int c = 0; c < 64; ++c) {
        const float xv = sX[r][c];
        a0 += xv * sW0[o][c];
        a1 += xv * sW1[o][c];
    }
    const size_t oidx = ((size_t)(b * NN + n0 + r)) * CC + o;
    yc[oidx] = a0;
    yr[oidx] = a1;
    if (r == 0)   // threads 0..63: column partial sum of this block's 4 rows
        partials[(size_t)blockIdx.x * 64 + o] =
            sX[0][o] + sX[1][o] + sX[2][o] + sX[3][o];
}

// Kernel 2 (tiny): reduce partials per batch -> xsum, then ysb[b,o] = xsum.W2[o,:] + bias[o]
__global__ void k_ysb(const float* __restrict__ partials, const float* __restrict__ W2,
                      const float* __restrict__ bias, float* __restrict__ ysb) {
    const int b = blockIdx.x;
    const int t = threadIdx.x;
    const int c = t & 63, g = t >> 6;   // 4 groups x 64 channels
    __shared__ float sPart[4][64];
    __shared__ float sXsum[64];
    float acc = 0.f;
    const float* pb = partials + (size_t)b * BPB * 64;
    for (int blk = g; blk < BPB; blk += 4)
        acc += pb[blk * 64 + c];
    sPart[g][c] = acc;
    __syncthreads();
    if (t < 64)
        sXsum[t] = sPart[0][t] + sPart[1][t] + sPart[2][t] + sPart[3][t];
    __syncthreads();
    if (t < 64) {
        float v = bias[t];               // bias shape (64,1) -> bias[o]
        const float* w = W2 + t * CC;
        #pragma unroll 8
        for (int cc = 0; cc < CC; ++cc) v += sXsum[cc] * w[cc];
        ysb[b * CC + t] = v;
    }
}

// Kernel 3: out[b,i,j,:] = yc[b,j,:] + yr[b,i,:] + ysb[b,:]
// IT=4 rows per block with block=256 (grid 1024): keeps 8 resident blocks/CU
// = 32 waves/CU (R5's IT=8/block=512 halved occupancy -> regression), while
// cutting yc L2-read traffic 4x (4.3 GB -> 1.07 GB).
__global__ void k_bcast(const float4* __restrict__ yc4, const float4* __restrict__ yr4,
                        const float4* __restrict__ ysb4, float4* __restrict__ out4) {
    const int t  = threadIdx.x;
    const int o4 = t & 15;
    const int j0 = t >> 4;              // 0..15
    const int b  = blockIdx.x / (NN / IT);
    const int i0 = (blockIdx.x % (NN / IT)) * IT;
    const float4 ys = ysb4[b * 16 + o4];
    float4 yrr[IT];
    #pragma unroll
    for (int r = 0; r < IT; ++r) {
        float4 v = yr4[(size_t)(b * NN + i0 + r) * 16 + o4];
        yrr[r].x = v.x + ys.x; yrr[r].y = v.y + ys.y;
        yrr[r].z = v.z + ys.z; yrr[r].w = v.w + ys.w;
    }
    const float4* ycb = yc4 + (size_t)b * NN * 16;
    float4* ob = out4 + (size_t)(b * NN + i0) * (NN * 16);
    #pragma unroll 2
    for (int j = j0; j < NN; j += 16) {
        float4 v = ycb[j * 16 + o4];
        #pragma unroll
        for (int r = 0; r < IT; ++r) {
            float4 w;
            w.x = v.x + yrr[r].x; w.y = v.y + yrr[r].y;
            w.z = v.z + yrr[r].z; w.w = v.w + yrr[r].w;
            __builtin_nontemporal_store(*(const f4_native*)&w,
                                        (f4_native*)&ob[(size_t)r * (NN * 16) + j * 16 + o4]);
        }
    }
}

extern "C" void kernel_launch(void* const* d_in, const int* in_sizes, int n_in,
                              void* d_out, int out_size, void* d_ws, size_t ws_size,
                              hipStream_t stream) {
    const float* x    = (const float*)d_in[0];
    // d_in[1] = adj (unused by forward)
    const float* W0   = (const float*)d_in[2];
    const float* W1   = (const float*)d_in[3];
    const float* W2   = (const float*)d_in[4];
    const float* bias = (const float*)d_in[5];
    float* out = (float*)d_out;

    float* ws       = (float*)d_ws;
    float* ysb      = ws;                                   // 256 floats
    float* yc       = ws + 256;                             // 262144 floats
    float* yr       = yc + NB * NN * CC;                    // 262144 floats
    float* partials = yr + NB * NN * CC;                    // 1024*64 = 65536 floats

    k_gemm<<<NB * BPB, 256, 0, stream>>>(x, W0, W1, yc, yr, partials);
    k_ysb<<<NB, 256, 0, stream>>>(partials, W2, bias, ysb);
    k_bcast<<<NB * (NN / IT), 256, 0, stream>>>((const float4*)yc, (const float4*)yr,
                                                (const float4*)ysb, (float4*)out);
}

// Round 7
// 231.017 us; speedup vs baseline: 1.0940x; 1.0382x over previous
//
#include <hip/hip_runtime.h>

#define NB 4
#define NN 1024
#define CC 64
#define BPB (NN / 4)   // gemm blocks per batch = 256
#define JC 256         // j-chunk per bcast block (held in registers: 16 float4/thread)
#define IC 32          // i-rows per bcast block (staged in LDS)

typedef float f4_native __attribute__((ext_vector_type(4)));

// Kernel 1: per 4-row block:
//   yc[b,n,o] = sum_c x[b,n,c]*W0[o,c]
//   yr[b,n,o] = sum_c x[b,n,c]*W1[o,c]
//   partials[blk,c] = sum over the block's 4 rows of x[.,c]
__global__ void k_gemm(const float* __restrict__ x, const float* __restrict__ W0,
                       const float* __restrict__ W1,
                       float* __restrict__ yc, float* __restrict__ yr,
                       float* __restrict__ partials) {
    __shared__ float sW0[64][65];   // +1 pad: stride-64 col reads would be 32-way bank conflict
    __shared__ float sW1[64][65];
    __shared__ float sX[4][64];
    const int t = threadIdx.x;
    const int b = blockIdx.x / BPB;
    const int n0 = (blockIdx.x % BPB) * 4;
    for (int idx = t; idx < 64 * 64; idx += 256) {
        sW0[idx >> 6][idx & 63] = W0[idx];
        sW1[idx >> 6][idx & 63] = W1[idx];
    }
    const int o = t & 63, r = t >> 6;
    sX[r][o] = x[((size_t)(b * NN + n0 + r)) * CC + o];
    __syncthreads();
    float a0 = 0.f, a1 = 0.f;
    #pragma unroll
    for (int c = 0; c < 64; ++c) {
        const float xv = sX[r][c];
        a0 += xv * sW0[o][c];
        a1 += xv * sW1[o][c];
    }
    const size_t oidx = ((size_t)(b * NN + n0 + r)) * CC + o;
    yc[oidx] = a0;
    yr[oidx] = a1;
    if (r == 0)   // threads 0..63: column partial sum of this block's 4 rows
        partials[(size_t)blockIdx.x * 64 + o] =
            sX[0][o] + sX[1][o] + sX[2][o] + sX[3][o];
}

// Kernel 2 (tiny): reduce partials per batch -> xsum, then ysb[b,o] = xsum.W2[o,:] + bias[o]
__global__ void k_ysb(const float* __restrict__ partials, const float* __restrict__ W2,
                      const float* __restrict__ bias, float* __restrict__ ysb) {
    const int b = blockIdx.x;
    const int t = threadIdx.x;
    const int c = t & 63, g = t >> 6;   // 4 groups x 64 channels
    __shared__ float sPart[4][64];
    __shared__ float sXsum[64];
    float acc = 0.f;
    const float* pb = partials + (size_t)b * BPB * 64;
    for (int blk = g; blk < BPB; blk += 4)
        acc += pb[blk * 64 + c];
    sPart[g][c] = acc;
    __syncthreads();
    if (t < 64)
        sXsum[t] = sPart[0][t] + sPart[1][t] + sPart[2][t] + sPart[3][t];
    __syncthreads();
    if (t < 64) {
        float v = bias[t];               // bias shape (64,1) -> bias[o]
        const float* w = W2 + t * CC;
        #pragma unroll 8
        for (int cc = 0; cc < CC; ++cc) v += sXsum[cc] * w[cc];
        ysb[b * CC + t] = v;
    }
}

// Kernel 3: out[b,i,j,:] = yc[b,j,:] + yr[b,i,:] + ysb[b,:]
// Load-free store loop: the block's yc j-chunk (JC=256 cols) lives in REGISTERS
// (ycreg[16], static unroll), yr+ysb for IC=32 rows lives in 8 KB LDS.
// Inner loop = 1 LDS broadcast read per i-row + 16 independent add+store pairs
// -> pure store stream (fill kernel proves 6.5 TB/s needs no loads in flight).
__global__ void k_bcast(const float4* __restrict__ yc4, const float4* __restrict__ yr4,
                        const float4* __restrict__ ysb4, float4* __restrict__ out4) {
    __shared__ float4 sYr[IC][16];
    const int t  = threadIdx.x;
    const int o4 = t & 15;
    const int bpb = (NN / JC) * (NN / IC);          // 128 blocks per batch
    const int b   = blockIdx.x / bpb;
    const int rem = blockIdx.x % bpb;
    const int j0  = (rem / (NN / IC)) * JC;
    const int i0  = (rem % (NN / IC)) * IC;

    // Register-preload yc chunk: ycreg[s] = yc[b, j0 + s*16 + (t>>4), o4] (coalesced: addr = s*256 + t)
    float4 ycreg[16];
    const float4* ycb = yc4 + ((size_t)b * NN + j0) * 16;
    #pragma unroll
    for (int s = 0; s < 16; ++s)
        ycreg[s] = ycb[s * 256 + t];

    // Stage yr + ysb for the i-rows (2 float4 per thread)
    const float4* yrb = yr4 + ((size_t)b * NN + i0) * 16;
    for (int idx = t; idx < IC * 16; idx += 256) {
        float4 v = yrb[idx];
        float4 ysv = ysb4[b * 16 + (idx & 15)];
        v.x += ysv.x; v.y += ysv.y; v.z += ysv.z; v.w += ysv.w;
        sYr[idx >> 4][idx & 15] = v;
    }
    __syncthreads();

    float4* ob = out4 + (((size_t)b * NN + i0) * NN + j0) * 16;
    for (int i = 0; i < IC; ++i) {
        const float4 yrv = sYr[i][o4];              // same-addr for 4 lanes -> broadcast, free
        float4* obi = ob + (size_t)i * (NN * 16);
        #pragma unroll
        for (int s = 0; s < 16; ++s) {
            float4 w;
            w.x = ycreg[s].x + yrv.x; w.y = ycreg[s].y + yrv.y;
            w.z = ycreg[s].z + yrv.z; w.w = ycreg[s].w + yrv.w;
            __builtin_nontemporal_store(*(const f4_native*)&w,
                                        (f4_native*)&obi[s * 256 + t]);
        }
    }
}

extern "C" void kernel_launch(void* const* d_in, const int* in_sizes, int n_in,
                              void* d_out, int out_size, void* d_ws, size_t ws_size,
                              hipStream_t stream) {
    const float* x    = (const float*)d_in[0];
    // d_in[1] = adj (unused by forward)
    const float* W0   = (const float*)d_in[2];
    const float* W1   = (const float*)d_in[3];
    const float* W2   = (const float*)d_in[4];
    const float* bias = (const float*)d_in[5];
    float* out = (float*)d_out;

    float* ws       = (float*)d_ws;
    float* ysb      = ws;                                   // 256 floats
    float* yc       = ws + 256;                             // 262144 floats
    float* yr       = yc + NB * NN * CC;                    // 262144 floats
    float* partials = yr + NB * NN * CC;                    // 1024*64 = 65536 floats

    k_gemm<<<NB * BPB, 256, 0, stream>>>(x, W0, W1, yc, yr, partials);
    k_ysb<<<NB, 256, 0, stream>>>(partials, W2, bias, ysb);
    k_bcast<<<NB * (NN / JC) * (NN / IC), 256, 0, stream>>>(
        (const float4*)yc, (const float4*)yr, (const float4*)ysb, (float4*)out);
}